// Round 19
// baseline (63.284 us; speedup 1.0000x reference)
//
#include <hip/hip_runtime.h>
#include <hip/hip_bf16.h>

// B=4, L=1024, H=512, NH=8, D=64
typedef __attribute__((ext_vector_type(8))) short bf16x8;
typedef __attribute__((ext_vector_type(4))) float f32x4;

__device__ __forceinline__ unsigned short f2bf(float f) {
    return __builtin_bit_cast(unsigned short, __float2bfloat16(f));
}

typedef const __attribute__((address_space(1))) void gvoid;
typedef __attribute__((address_space(3))) void lvoid;
#define GLDS(g, s) __builtin_amdgcn_global_load_lds((gvoid*)(g), (lvoid*)(s), 16, 0, 0)

__device__ __forceinline__ void block_barrier() {
    asm volatile("" ::: "memory");
    __builtin_amdgcn_s_barrier();
    asm volatile("" ::: "memory");
}

// ---------------- projection GEMM: C[m,n] = X[m,:]·W[n,:] + b[n] -------------
// ROUND-16 VERBATIM (BK=32, 1-deep prefetch, 768 blocks).
// z=0: query->Qb [b][h][l][d], z=1: key->Kb [b][h][l][d], z=2: value->Vt [b][h][d][l]
__global__ __launch_bounds__(256) void proj_kernel(
    const float* __restrict__ query, const float* __restrict__ key_, const float* __restrict__ value,
    const float* __restrict__ wq_w, const float* __restrict__ wq_b,
    const float* __restrict__ wk_w, const float* __restrict__ wk_b,
    const float* __restrict__ wv_w, const float* __restrict__ wv_b,
    unsigned short* __restrict__ Qb, unsigned short* __restrict__ Kb, unsigned short* __restrict__ Vt)
{
    const int wid = (blockIdx.x & 7) * 96 + (blockIdx.x >> 3);   // bijective, 96/XCD
    const int z  = wid >> 8;
    const int rr = wid & 255;
    const int by = rr >> 3, bx = rr & 7;

    const float* X    = (z == 0) ? query : (z == 1) ? key_ : value;
    const float* W    = (z == 0) ? wq_w  : (z == 1) ? wk_w : wv_w;
    const float* bias = (z == 0) ? wq_b  : (z == 1) ? wk_b : wv_b;

    const int t = threadIdx.x;
    const int l = t & 63;
    const int w = t >> 6;
    const int wm = w >> 1, wn = w & 1;       // 2x2 wave grid, 64x32 per wave
    const int m0 = by * 128, n0 = bx * 64;

    __shared__ __align__(16) unsigned short As[128 * 32];
    __shared__ __align__(16) unsigned short Bs[64 * 32];

    f32x4 acc[4][2];
#pragma unroll
    for (int i = 0; i < 4; i++)
#pragma unroll
        for (int j = 0; j < 2; j++) acc[i][j] = (f32x4){0.f, 0.f, 0.f, 0.f};

    float4 ra[4], rb[2];
    auto LOAD = [&](int k0) {
#pragma unroll
        for (int i = 0; i < 4; i++) {
            int idx = t + 256 * i;
            int row = idx >> 3, c = idx & 7;
            ra[i] = *(const float4*)(X + (size_t)(m0 + row) * 512 + k0 + c * 4);
        }
#pragma unroll
        for (int i = 0; i < 2; i++) {
            int idx = t + 256 * i;
            int row = idx >> 3, c = idx & 7;
            rb[i] = *(const float4*)(W + (size_t)(n0 + row) * 512 + k0 + c * 4);
        }
    };
    LOAD(0);

    for (int k0 = 0; k0 < 512; k0 += 32) {
        if (k0) block_barrier();             // prev frag reads consumed by MFMAs
#pragma unroll
        for (int i = 0; i < 4; i++) {
            int idx = t + 256 * i;
            int row = idx >> 3, c = idx & 7;
            __align__(8) unsigned short va[4] = {f2bf(ra[i].x), f2bf(ra[i].y), f2bf(ra[i].z), f2bf(ra[i].w)};
            *(uint2*)(As + row * 32 + (((c >> 1) ^ (row & 3)) * 8) + (c & 1) * 4) = *(uint2*)va;
        }
#pragma unroll
        for (int i = 0; i < 2; i++) {
            int idx = t + 256 * i;
            int row = idx >> 3, c = idx & 7;
            __align__(8) unsigned short vb[4] = {f2bf(rb[i].x), f2bf(rb[i].y), f2bf(rb[i].z), f2bf(rb[i].w)};
            *(uint2*)(Bs + row * 32 + (((c >> 1) ^ (row & 3)) * 8) + (c & 1) * 4) = *(uint2*)vb;
        }
        asm volatile("s_waitcnt lgkmcnt(0)" ::: "memory");
        block_barrier();
        if (k0 + 32 < 512) LOAD(k0 + 32);    // prefetch overlaps MFMA below

        bf16x8 af[4], bfv[2];
#pragma unroll
        for (int mf = 0; mf < 4; mf++) {
            int row = wm * 64 + mf * 16 + (l & 15);
            af[mf] = *(const bf16x8*)(As + row * 32 + (((l >> 4) ^ (row & 3)) * 8));
        }
#pragma unroll
        for (int nf = 0; nf < 2; nf++) {
            int row = wn * 32 + nf * 16 + (l & 15);
            bfv[nf] = *(const bf16x8*)(Bs + row * 32 + (((l >> 4) ^ (row & 3)) * 8));
        }
#pragma unroll
        for (int mf = 0; mf < 4; mf++)
#pragma unroll
            for (int nf = 0; nf < 2; nf++)
                acc[mf][nf] = __builtin_amdgcn_mfma_f32_16x16x32_bf16(af[mf], bfv[nf], acc[mf][nf], 0, 0, 0);
    }

    if (z < 2) {
        unsigned short* dst = (z == 0) ? Qb : Kb;
#pragma unroll
        for (int nf = 0; nf < 2; nf++) {
            int n = n0 + wn * 32 + nf * 16 + (l & 15);
            float bv = bias[n];
            int h = n >> 6, d = n & 63;
#pragma unroll
            for (int mf = 0; mf < 4; mf++) {
                int mbase = m0 + wm * 64 + mf * 16 + 4 * (l >> 4);
                int bb = mbase >> 10;
#pragma unroll
                for (int r = 0; r < 4; r++) {
                    int lq = (mbase + r) & 1023;
                    dst[((size_t)(bb * 8 + h) * 1024 + lq) * 64 + d] = f2bf(acc[mf][nf][r] + bv);
                }
            }
        }
    } else {
#pragma unroll
        for (int nf = 0; nf < 2; nf++) {
            int n = n0 + wn * 32 + nf * 16 + (l & 15);
            float bv = bias[n];
            int h = n >> 6, d = n & 63;
#pragma unroll
            for (int mf = 0; mf < 4; mf++) {
                int mbase = m0 + wm * 64 + mf * 16 + 4 * (l >> 4);
                int bb = mbase >> 10;
                int lq0 = mbase & 1023;                 // 4 consecutive l positions
                ushort4 pk;
                pk.x = f2bf(acc[mf][nf][0] + bv);
                pk.y = f2bf(acc[mf][nf][1] + bv);
                pk.z = f2bf(acc[mf][nf][2] + bv);
                pk.w = f2bf(acc[mf][nf][3] + bv);
                *(ushort4*)(Vt + ((size_t)(bb * 8 + h) * 64 + d) * 1024 + lq0) = pk;
            }
        }
    }
}

// ---------------- fused attention: per (b, h, 64-row q tile), KVBLK=128 ------
// r16 base + exp2 w/ pre-scaled REL + full-tile fast path.
// Denominator = r16's proven f32 shfl-sum (ones-MFMA dropped — r18 regression).
__global__ __launch_bounds__(256, 2) void attn_kernel(
    const unsigned short* __restrict__ Qb, const unsigned short* __restrict__ Kb,
    const unsigned short* __restrict__ Vt, const float* __restrict__ rel_pos,
    const int* __restrict__ seq_len, const int* __restrict__ lex_num,
    unsigned short* __restrict__ AO)
{
    const int t = threadIdx.x;
    const int l = t & 63;
    const int w = t >> 6;                    // wave 0..3, owns 16 q rows
    const int wid = (blockIdx.x & 7) * 64 + (blockIdx.x >> 3);
    const int x8 = wid >> 6;
    const int g  = (wid >> 4) & 3;
    const int qt = wid & 15;
    const int b  = g;
    const int h  = (x8 + 2 * g) & 7;
    const int q0 = qt * 64;
    const int bh = b * 8 + h;
    const int len = seq_len[b] + lex_num[b];
    const int nkt = (len + 127) >> 7;        // 128-key tiles with >=1 valid key

    __shared__ __align__(16) unsigned short Qs[64 * 64];        //  8 KB
    __shared__ __align__(16) unsigned short Ks[2][128 * 64];    // 32 KB [k][d]
    __shared__ __align__(16) unsigned short Vs[64 * 128];       // 16 KB [d][k]
    __shared__ __align__(16) unsigned short Ps[4 * 16 * 128];   // 16 KB per-wave [q][k]

    const unsigned short* Qg = Qb + ((size_t)bh * 1024 + q0) * 64;
    const unsigned short* Kg = Kb + (size_t)bh * 1024 * 64;
    const unsigned short* Vg = Vt + (size_t)bh * 64 * 1024;
    const float* Rg = rel_pos + ((size_t)bh * 1024 + q0) * 1024;

    // staging geometry (GLDS dest = wave-uniform base + lane*16B; swizzle the SOURCE)
    const int rl8 = l >> 3, c8 = l & 7;      // 64-short rows: 8 rows x 8 chunks
    const int kvc = (c8 ^ rl8) * 8;
    const int rl4 = l >> 4, c16 = l & 15;    // 128-short rows: 4 rows x 16 chunks

    auto STAGE_K = [&](int kt2, int nb) {    // 4 GLDS: K tile [128][64]
        const int k0s = kt2 * 128;
#pragma unroll
        for (int j = 0; j < 4; j++) {
            int row = j * 32 + w * 8 + rl8;  // row&7 == rl8
            GLDS(Kg + (size_t)(k0s + row) * 64 + kvc, &Ks[nb][(j * 32 + w * 8) * 64]);
        }
    };
    auto STAGE_V = [&](int kt2) {            // 4 GLDS: V^T tile [64][128]
        const int k0s = kt2 * 128;
#pragma unroll
        for (int j = 0; j < 4; j++) {
            int drow = j * 16 + w * 4 + rl4; // drow&15 == w*4+rl4
            int sc = (c16 ^ (w * 4 + rl4)) * 8;
            GLDS(Vg + (size_t)drow * 1024 + k0s + sc, &Vs[(j * 16 + w * 4) * 128]);
        }
    };
    // R[r*8+kn] = rel[...]*log2e - 16*log2e (constants folded off critical path)
    auto RELLOAD = [&](float (&R)[32], int kt2) {
        const float* rp = Rg + (size_t)(w * 16 + 4 * (l >> 4)) * 1024 + kt2 * 128 + (l & 15);
#pragma unroll
        for (int r = 0; r < 4; r++)
#pragma unroll
            for (int kn = 0; kn < 8; kn++)
                R[r * 8 + kn] = fmaf(rp[(size_t)r * 1024 + kn * 16], 1.44269504f, -23.08312065f);
    };

    float rA[32], rB[32];
    // prologue order (vmcnt ledger): Q(2), K0(4), relA(32), V0(4)
#pragma unroll
    for (int j = 0; j < 2; j++) {
        int row = w * 16 + j * 8 + rl8;
        GLDS(Qg + (size_t)row * 64 + kvc, &Qs[(w * 16 + j * 8) * 64]);
    }
    STAGE_K(0, 0);
    RELLOAD(rA, 0);
    STAGE_V(0);

    bf16x8 qf[2];
    f32x4 oacc[4];
#pragma unroll
    for (int dn = 0; dn < 4; dn++) oacc[dn] = (f32x4){0.f, 0.f, 0.f, 0.f};
    float l_run[4] = {0.f, 0.f, 0.f, 0.f};
    unsigned short* Pw = Ps + w * 16 * 128;

    auto tile_body = [&](int kt, float (&REL)[32], float (&RELN)[32]) {
        const int cur = kt & 1;
        const int k0 = kt * 128;
        if (kt + 1 < nkt) {
            STAGE_K(kt + 1, cur ^ 1);        // +4  (buf not read this tile)
            RELLOAD(RELN, kt + 1);           // +32
            // need K(kt)+REL(kt) landed; newer = V(kt)4 + K(kt+1)4 + REL(kt+1)32
            asm volatile("s_waitcnt vmcnt(40)" ::: "memory");
        } else {
            asm volatile("s_waitcnt vmcnt(4)" ::: "memory");
        }
        block_barrier();                     // barrier1: K[cur] visible to all waves

        if (kt == 0) {
#pragma unroll
            for (int s = 0; s < 2; s++) {
                int row = w * 16 + (l & 15);
                int ch = 4 * s + (l >> 4);
                qf[s] = *(const bf16x8*)(Qs + row * 64 + ((ch ^ (row & 7)) * 8));
            }
        }

        const unsigned short* Ksc = Ks[cur];

        f32x4 sa[8];
#pragma unroll
        for (int kn = 0; kn < 8; kn++) sa[kn] = (f32x4){0.f, 0.f, 0.f, 0.f};
        __builtin_amdgcn_s_setprio(1);
#pragma unroll
        for (int s = 0; s < 2; s++)
#pragma unroll
            for (int kn = 0; kn < 8; kn++) {
                int krow = kn * 16 + (l & 15);
                int ch = 4 * s + (l >> 4);
                bf16x8 kf = *(const bf16x8*)(Ksc + krow * 64 + ((ch ^ (krow & 7)) * 8));
                sa[kn] = __builtin_amdgcn_mfma_f32_16x16x32_bf16(qf[s], kf, sa[kn], 0, 0, 0);
            }
        __builtin_amdgcn_s_setprio(0);

        // fixed-offset softmax: p = exp2(sa*0.125*log2e + REL'); shfl-sum denom
        const bool full = (k0 + 128 <= len);
#pragma unroll
        for (int r = 0; r < 4; r++) {
            int qrow = 4 * (l >> 4) + r;
            float pr[8], rs = 0.f;
            if (full) {
#pragma unroll
                for (int kn = 0; kn < 8; kn++) {
                    pr[kn] = exp2f(fmaf(sa[kn][r], 0.18033688f, REL[r * 8 + kn]));
                    rs += pr[kn];
                }
            } else {
#pragma unroll
                for (int kn = 0; kn < 8; kn++) {
                    int kg = k0 + kn * 16 + (l & 15);
                    pr[kn] = (kg < len) ? exp2f(fmaf(sa[kn][r], 0.18033688f, REL[r * 8 + kn])) : 0.0f;
                    rs += pr[kn];
                }
            }
#pragma unroll
            for (int o = 1; o < 16; o <<= 1) rs += __shfl_xor(rs, o, 64);
            l_run[r] += rs;
#pragma unroll
            for (int kn = 0; kn < 8; kn++) {
                int ck = (kn * 2 + ((l >> 3) & 1)) ^ (qrow & 15);
                Pw[qrow * 128 + ck * 8 + (l & 7)] = f2bf(pr[kn]);
            }
        }

        if (kt + 1 < nkt) {
            // need V(kt) landed; newer = K(kt+1)4 + REL(kt+1)32
            asm volatile("s_waitcnt vmcnt(36)" ::: "memory");
        } else {
            asm volatile("s_waitcnt vmcnt(0)" ::: "memory");
        }
        block_barrier();                     // barrier2: V visible to all waves

        // PV: out[q][d] += P[q,k]·V[k,d]
        __builtin_amdgcn_s_setprio(1);
#pragma unroll
        for (int s = 0; s < 4; s++) {
            int arow = (l & 15);
            bf16x8 pf = *(const bf16x8*)(Pw + arow * 128 + (((s * 4 + (l >> 4)) ^ arow) * 8));
#pragma unroll
            for (int dn = 0; dn < 4; dn++) {
                int drow = dn * 16 + (l & 15);
                bf16x8 vf = *(const bf16x8*)(Vs + drow * 128 + (((s * 4 + (l >> 4)) ^ (drow & 15)) * 8));
                oacc[dn] = __builtin_amdgcn_mfma_f32_16x16x32_bf16(pf, vf, oacc[dn], 0, 0, 0);
            }
        }
        __builtin_amdgcn_s_setprio(0);
        block_barrier();                     // barrier3: all PV reads of Vs done
        if (kt + 1 < nkt) STAGE_V(kt + 1);   // +4 overwrite Vs (covered by next vmcnt(36))
    };

    for (int kt = 0; kt < nkt; kt += 2) {
        tile_body(kt, rA, rB);
        if (kt + 1 < nkt) tile_body(kt + 1, rB, rA);
    }

    // epilogue: normalize, store bf16 to AO[b*1024+q][h*64+d]
    unsigned short* AOg = AO + ((size_t)(b * 1024 + q0 + w * 16)) * 512 + h * 64;
#pragma unroll
    for (int r = 0; r < 4; r++) {
        float inv = 1.0f / l_run[r];
        int qrow = 4 * (l >> 4) + r;
#pragma unroll
        for (int dn = 0; dn < 4; dn++)
            AOg[(size_t)qrow * 512 + dn * 16 + (l & 15)] = f2bf(oacc[dn][r] * inv);
    }
}

// ---------------- FF GEMM: out[m,n] = AO[m,:]·ff_w[n,:] + ff_b[n] (f32 out) ---
// ROUND-16 VERBATIM (BK=32). 64x64 tiles -> 512 blocks = 2/CU.
__global__ __launch_bounds__(256) void ff_kernel(
    const unsigned short* __restrict__ AO, const float* __restrict__ ff_w,
    const float* __restrict__ ff_b, float* __restrict__ out)
{
    const int t = threadIdx.x;
    const int l = t & 63;
    const int w = t >> 6;
    const int wm = w >> 1, wn = w & 1;       // 2x2 waves of 32x32
    const int wid = (blockIdx.x & 7) * 64 + (blockIdx.x >> 3);
    const int by = wid >> 3;                 // m tile (4096/64)
    const int bx = wid & 7;                  // n tile (512/64)
    const int m0 = by * 64, n0 = bx * 64;

    __shared__ __align__(16) unsigned short As[64 * 32];
    __shared__ __align__(16) unsigned short Bs[64 * 32];

    f32x4 acc[2][2];
#pragma unroll
    for (int i = 0; i < 2; i++)
#pragma unroll
        for (int j = 0; j < 2; j++) acc[i][j] = (f32x4){0.f, 0.f, 0.f, 0.f};

    uint4 ua;
    float4 rbf[2];
    const int arow = t >> 2, ac = t & 3;
    auto LOAD = [&](int k0) {
        ua = *(const uint4*)(AO + (size_t)(m0 + arow) * 512 + k0 + ac * 8);
#pragma unroll
        for (int i = 0; i < 2; i++) {
            int idx = t + 256 * i;
            int row = idx >> 3, c = idx & 7;
            rbf[i] = *(const float4*)(ff_w + (size_t)(n0 + row) * 512 + k0 + c * 4);
        }
    };
    LOAD(0);

    for (int k0 = 0; k0 < 512; k0 += 32) {
        if (k0) block_barrier();
        *(uint4*)(As + arow * 32 + ((ac ^ (arow & 3)) * 8)) = ua;
#pragma unroll
        for (int i = 0; i < 2; i++) {
            int idx = t + 256 * i;
            int row = idx >> 3, c = idx & 7;
            __align__(8) unsigned short vb[4] = {f2bf(rbf[i].x), f2bf(rbf[i].y), f2bf(rbf[i].z), f2bf(rbf[i].w)};
            *(uint2*)(Bs + row * 32 + (((c >> 1) ^ (row & 3)) * 8) + (c & 1) * 4) = *(uint2*)vb;
        }
        asm volatile("s_waitcnt lgkmcnt(0)" ::: "memory");
        block_barrier();
        if (k0 + 32 < 512) LOAD(k0 + 32);

        bf16x8 af[2], bfv[2];
#pragma unroll
        for (int mf = 0; mf < 2; mf++) {
            int row = wm * 32 + mf * 16 + (l & 15);
            af[mf] = *(const bf16x8*)(As + row * 32 + (((l >> 4) ^ (row & 3)) * 8));
        }
#pragma unroll
        for (int nf = 0; nf < 2; nf++) {
            int row = wn * 32 + nf * 16 + (l & 15);
            bfv[nf] = *(const bf16x8*)(Bs + row * 32 + (((l >> 4) ^ (row & 3)) * 8));
        }
#pragma unroll
        for (int mf = 0; mf < 2; mf++)
#pragma unroll
            for (int nf = 0; nf < 2; nf++)
                acc[mf][nf] = __builtin_amdgcn_mfma_f32_16x16x32_bf16(af[mf], bfv[nf], acc[mf][nf], 0, 0, 0);
    }

#pragma unroll
    for (int nf = 0; nf < 2; nf++) {
        int n = n0 + wn * 32 + nf * 16 + (l & 15);
        float bv = ff_b[n];
#pragma unroll
        for (int mf = 0; mf < 2; mf++) {
            int mbase = m0 + wm * 32 + mf * 16 + 4 * (l >> 4);
#pragma unroll
            for (int r = 0; r < 4; r++)
                out[(size_t)(mbase + r) * 512 + n] = acc[mf][nf][r] + bv;
        }
    }
}

extern "C" void kernel_launch(void* const* d_in, const int* in_sizes, int n_in,
                              void* d_out, int out_size, void* d_ws, size_t ws_size,
                              hipStream_t stream) {
    const float* key   = (const float*)d_in[0];
    const float* query = (const float*)d_in[1];
    const float* value = (const float*)d_in[2];
    const float* rel   = (const float*)d_in[3];
    const float* wk_w  = (const float*)d_in[4];
    const float* wk_b  = (const float*)d_in[5];
    const float* wq_w  = (const float*)d_in[6];
    const float* wq_b  = (const float*)d_in[7];
    const float* wv_w  = (const float*)d_in[8];
    const float* wv_b  = (const float*)d_in[9];
    const float* ff_w  = (const float*)d_in[10];
    const float* ff_b  = (const float*)d_in[11];
    const int* seq_len = (const int*)d_in[12];
    const int* lex_num = (const int*)d_in[13];
    float* out = (float*)d_out;

    unsigned short* Qb = (unsigned short*)d_ws;     // [4][8][1024][64] bf16, 4 MB
    unsigned short* Kb = Qb + 2097152;              // 4 MB
    unsigned short* Vt = Kb + 2097152;              // [4][8][64][1024] bf16, 4 MB
    unsigned short* AO = Vt + 2097152;              // [4096][512] bf16, 4 MB

    proj_kernel<<<dim3(768), 256, 0, stream>>>(query, key, value,
                                               wq_w, wq_b, wk_w, wk_b, wv_w, wv_b,
                                               Qb, Kb, Vt);
    attn_kernel<<<dim3(512), 256, 0, stream>>>(Qb, Kb, Vt, rel, seq_len, lex_num, AO);
    ff_kernel<<<dim3(512), 256, 0, stream>>>(AO, ff_w, ff_b, out);
}

// Round 20
// 57.264 us; speedup vs baseline: 1.1051x; 1.1051x over previous
//
#include <hip/hip_runtime.h>
#include <hip/hip_bf16.h>

// B=4, L=1024, H=512, NH=8, D=64
typedef __attribute__((ext_vector_type(8))) short bf16x8;
typedef __attribute__((ext_vector_type(4))) float f32x4;

__device__ __forceinline__ unsigned short f2bf(float f) {
    return __builtin_bit_cast(unsigned short, __float2bfloat16(f));
}

typedef const __attribute__((address_space(1))) void gvoid;
typedef __attribute__((address_space(3))) void lvoid;
#define GLDS(g, s) __builtin_amdgcn_global_load_lds((gvoid*)(g), (lvoid*)(s), 16, 0, 0)

__device__ __forceinline__ void block_barrier() {
    asm volatile("" ::: "memory");
    __builtin_amdgcn_s_barrier();
    asm volatile("" ::: "memory");
}

// ---------------- projection GEMM: C[m,n] = X[m,:]·W[n,:] + b[n] -------------
// BM=128, BN=64, BK=32, 768 blocks = 3/CU, 1-deep prefetch (r16 green).
// z=0: query->Qb [b][h][l][d], z=1: key->Kb [b][h][l][d], z=2: value->Vt [b][h][d][l]
__global__ __launch_bounds__(256) void proj_kernel(
    const float* __restrict__ query, const float* __restrict__ key_, const float* __restrict__ value,
    const float* __restrict__ wq_w, const float* __restrict__ wq_b,
    const float* __restrict__ wk_w, const float* __restrict__ wk_b,
    const float* __restrict__ wv_w, const float* __restrict__ wv_b,
    unsigned short* __restrict__ Qb, unsigned short* __restrict__ Kb, unsigned short* __restrict__ Vt)
{
    const int wid = (blockIdx.x & 7) * 96 + (blockIdx.x >> 3);   // bijective, 96/XCD
    const int z  = wid >> 8;
    const int rr = wid & 255;
    const int by = rr >> 3, bx = rr & 7;

    const float* X    = (z == 0) ? query : (z == 1) ? key_ : value;
    const float* W    = (z == 0) ? wq_w  : (z == 1) ? wk_w : wv_w;
    const float* bias = (z == 0) ? wq_b  : (z == 1) ? wk_b : wv_b;

    const int t = threadIdx.x;
    const int l = t & 63;
    const int w = t >> 6;
    const int wm = w >> 1, wn = w & 1;       // 2x2 wave grid, 64x32 per wave
    const int m0 = by * 128, n0 = bx * 64;

    __shared__ __align__(16) unsigned short As[128 * 32];
    __shared__ __align__(16) unsigned short Bs[64 * 32];

    f32x4 acc[4][2];
#pragma unroll
    for (int i = 0; i < 4; i++)
#pragma unroll
        for (int j = 0; j < 2; j++) acc[i][j] = (f32x4){0.f, 0.f, 0.f, 0.f};

    float4 ra[4], rb[2];
    auto LOAD = [&](int k0) {
#pragma unroll
        for (int i = 0; i < 4; i++) {
            int idx = t + 256 * i;
            int row = idx >> 3, c = idx & 7;
            ra[i] = *(const float4*)(X + (size_t)(m0 + row) * 512 + k0 + c * 4);
        }
#pragma unroll
        for (int i = 0; i < 2; i++) {
            int idx = t + 256 * i;
            int row = idx >> 3, c = idx & 7;
            rb[i] = *(const float4*)(W + (size_t)(n0 + row) * 512 + k0 + c * 4);
        }
    };
    LOAD(0);

    for (int k0 = 0; k0 < 512; k0 += 32) {
        if (k0) block_barrier();             // prev frag reads consumed by MFMAs
#pragma unroll
        for (int i = 0; i < 4; i++) {
            int idx = t + 256 * i;
            int row = idx >> 3, c = idx & 7;
            __align__(8) unsigned short va[4] = {f2bf(ra[i].x), f2bf(ra[i].y), f2bf(ra[i].z), f2bf(ra[i].w)};
            *(uint2*)(As + row * 32 + (((c >> 1) ^ (row & 3)) * 8) + (c & 1) * 4) = *(uint2*)va;
        }
#pragma unroll
        for (int i = 0; i < 2; i++) {
            int idx = t + 256 * i;
            int row = idx >> 3, c = idx & 7;
            __align__(8) unsigned short vb[4] = {f2bf(rb[i].x), f2bf(rb[i].y), f2bf(rb[i].z), f2bf(rb[i].w)};
            *(uint2*)(Bs + row * 32 + (((c >> 1) ^ (row & 3)) * 8) + (c & 1) * 4) = *(uint2*)vb;
        }
        asm volatile("s_waitcnt lgkmcnt(0)" ::: "memory");
        block_barrier();
        if (k0 + 32 < 512) LOAD(k0 + 32);    // prefetch overlaps MFMA below

        bf16x8 af[4], bfv[2];
#pragma unroll
        for (int mf = 0; mf < 4; mf++) {
            int row = wm * 64 + mf * 16 + (l & 15);
            af[mf] = *(const bf16x8*)(As + row * 32 + (((l >> 4) ^ (row & 3)) * 8));
        }
#pragma unroll
        for (int nf = 0; nf < 2; nf++) {
            int row = wn * 32 + nf * 16 + (l & 15);
            bfv[nf] = *(const bf16x8*)(Bs + row * 32 + (((l >> 4) ^ (row & 3)) * 8));
        }
#pragma unroll
        for (int mf = 0; mf < 4; mf++)
#pragma unroll
            for (int nf = 0; nf < 2; nf++)
                acc[mf][nf] = __builtin_amdgcn_mfma_f32_16x16x32_bf16(af[mf], bfv[nf], acc[mf][nf], 0, 0, 0);
    }

    if (z < 2) {
        unsigned short* dst = (z == 0) ? Qb : Kb;
#pragma unroll
        for (int nf = 0; nf < 2; nf++) {
            int n = n0 + wn * 32 + nf * 16 + (l & 15);
            float bv = bias[n];
            int h = n >> 6, d = n & 63;
#pragma unroll
            for (int mf = 0; mf < 4; mf++) {
                int mbase = m0 + wm * 64 + mf * 16 + 4 * (l >> 4);
                int bb = mbase >> 10;
#pragma unroll
                for (int r = 0; r < 4; r++) {
                    int lq = (mbase + r) & 1023;
                    dst[((size_t)(bb * 8 + h) * 1024 + lq) * 64 + d] = f2bf(acc[mf][nf][r] + bv);
                }
            }
        }
    } else {
#pragma unroll
        for (int nf = 0; nf < 2; nf++) {
            int n = n0 + wn * 32 + nf * 16 + (l & 15);
            float bv = bias[n];
            int h = n >> 6, d = n & 63;
#pragma unroll
            for (int mf = 0; mf < 4; mf++) {
                int mbase = m0 + wm * 64 + mf * 16 + 4 * (l >> 4);
                int bb = mbase >> 10;
                int lq0 = mbase & 1023;                 // 4 consecutive l positions
                ushort4 pk;
                pk.x = f2bf(acc[mf][nf][0] + bv);
                pk.y = f2bf(acc[mf][nf][1] + bv);
                pk.z = f2bf(acc[mf][nf][2] + bv);
                pk.w = f2bf(acc[mf][nf][3] + bv);
                *(ushort4*)(Vt + ((size_t)(bb * 8 + h) * 64 + d) * 1024 + lq0) = pk;
            }
        }
    }
}

// ---------------- fused attention: per (b, h, 64-row q tile), KVBLK=128 ------
// FIXED-OFFSET softmax p = __expf(s - 16) (no max tracking, no O-rescale;
// denominator = f32 shfl-sum). r16 green configuration.
__global__ __launch_bounds__(256, 2) void attn_kernel(
    const unsigned short* __restrict__ Qb, const unsigned short* __restrict__ Kb,
    const unsigned short* __restrict__ Vt, const float* __restrict__ rel_pos,
    const int* __restrict__ seq_len, const int* __restrict__ lex_num,
    unsigned short* __restrict__ AO)
{
    const int t = threadIdx.x;
    const int l = t & 63;
    const int w = t >> 6;                    // wave 0..3, owns 16 q rows
    const int wid = (blockIdx.x & 7) * 64 + (blockIdx.x >> 3);
    const int x8 = wid >> 6;
    const int g  = (wid >> 4) & 3;
    const int qt = wid & 15;
    const int b  = g;
    const int h  = (x8 + 2 * g) & 7;
    const int q0 = qt * 64;
    const int bh = b * 8 + h;
    const int len = seq_len[b] + lex_num[b];
    const int nkt = (len + 127) >> 7;        // 128-key tiles with >=1 valid key

    __shared__ __align__(16) unsigned short Qs[64 * 64];        //  8 KB
    __shared__ __align__(16) unsigned short Ks[2][128 * 64];    // 32 KB [k][d]
    __shared__ __align__(16) unsigned short Vs[64 * 128];       // 16 KB [d][k]
    __shared__ __align__(16) unsigned short Ps[4 * 16 * 128];   // 16 KB per-wave [q][k]

    const unsigned short* Qg = Qb + ((size_t)bh * 1024 + q0) * 64;
    const unsigned short* Kg = Kb + (size_t)bh * 1024 * 64;
    const unsigned short* Vg = Vt + (size_t)bh * 64 * 1024;
    const float* Rg = rel_pos + ((size_t)bh * 1024 + q0) * 1024;

    // staging geometry (GLDS dest = wave-uniform base + lane*16B; swizzle the SOURCE)
    const int rl8 = l >> 3, c8 = l & 7;      // 64-short rows: 8 rows x 8 chunks
    const int kvc = (c8 ^ rl8) * 8;
    const int rl4 = l >> 4, c16 = l & 15;    // 128-short rows: 4 rows x 16 chunks

    auto STAGE_K = [&](int kt2, int nb) {    // 4 GLDS: K tile [128][64]
        const int k0s = kt2 * 128;
#pragma unroll
        for (int j = 0; j < 4; j++) {
            int row = j * 32 + w * 8 + rl8;  // row&7 == rl8
            GLDS(Kg + (size_t)(k0s + row) * 64 + kvc, &Ks[nb][(j * 32 + w * 8) * 64]);
        }
    };
    auto STAGE_V = [&](int kt2) {            // 4 GLDS: V^T tile [64][128]
        const int k0s = kt2 * 128;
#pragma unroll
        for (int j = 0; j < 4; j++) {
            int drow = j * 16 + w * 4 + rl4; // drow&15 == w*4+rl4
            int sc = (c16 ^ (w * 4 + rl4)) * 8;
            GLDS(Vg + (size_t)drow * 1024 + k0s + sc, &Vs[(j * 16 + w * 4) * 128]);
        }
    };
    // R[r*8+kn] = rel[q0 + w*16 + 4*(l>>4) + r][kt2*128 + kn*16 + (l&15)]  (32 loads)
    auto RELLOAD = [&](float (&R)[32], int kt2) {
        const float* rp = Rg + (size_t)(w * 16 + 4 * (l >> 4)) * 1024 + kt2 * 128 + (l & 15);
#pragma unroll
        for (int r = 0; r < 4; r++)
#pragma unroll
            for (int kn = 0; kn < 8; kn++)
                R[r * 8 + kn] = rp[(size_t)r * 1024 + kn * 16];
    };

    float rA[32], rB[32];
    // prologue order (vmcnt ledger): Q(2), K0(4), relA(32), V0(4)
#pragma unroll
    for (int j = 0; j < 2; j++) {
        int row = w * 16 + j * 8 + rl8;
        GLDS(Qg + (size_t)row * 64 + kvc, &Qs[(w * 16 + j * 8) * 64]);
    }
    STAGE_K(0, 0);
    RELLOAD(rA, 0);
    STAGE_V(0);

    bf16x8 qf[2];
    f32x4 oacc[4];
#pragma unroll
    for (int dn = 0; dn < 4; dn++) oacc[dn] = (f32x4){0.f, 0.f, 0.f, 0.f};
    float l_run[4] = {0.f, 0.f, 0.f, 0.f};
    unsigned short* Pw = Ps + w * 16 * 128;

    auto tile_body = [&](int kt, float (&REL)[32], float (&RELN)[32]) {
        const int cur = kt & 1;
        const int k0 = kt * 128;
        if (kt + 1 < nkt) {
            STAGE_K(kt + 1, cur ^ 1);        // +4  (buf not read this tile)
            RELLOAD(RELN, kt + 1);           // +32
            // need K(kt)+REL(kt) landed; newer = V(kt)4 + K(kt+1)4 + REL(kt+1)32
            asm volatile("s_waitcnt vmcnt(40)" ::: "memory");
        } else {
            asm volatile("s_waitcnt vmcnt(4)" ::: "memory");
        }
        block_barrier();                     // barrier1: K[cur] visible to all waves

        if (kt == 0) {
#pragma unroll
            for (int s = 0; s < 2; s++) {
                int row = w * 16 + (l & 15);
                int ch = 4 * s + (l >> 4);
                qf[s] = *(const bf16x8*)(Qs + row * 64 + ((ch ^ (row & 7)) * 8));
            }
        }

        const unsigned short* Ksc = Ks[cur];

        f32x4 sa[8];
#pragma unroll
        for (int kn = 0; kn < 8; kn++) sa[kn] = (f32x4){0.f, 0.f, 0.f, 0.f};
        __builtin_amdgcn_s_setprio(1);
#pragma unroll
        for (int s = 0; s < 2; s++)
#pragma unroll
            for (int kn = 0; kn < 8; kn++) {
                int krow = kn * 16 + (l & 15);
                int ch = 4 * s + (l >> 4);
                bf16x8 kf = *(const bf16x8*)(Ksc + krow * 64 + ((ch ^ (krow & 7)) * 8));
                sa[kn] = __builtin_amdgcn_mfma_f32_16x16x32_bf16(qf[s], kf, sa[kn], 0, 0, 0);
            }
        __builtin_amdgcn_s_setprio(0);

        // fixed-offset softmax: p = exp(s - 16); f32 shfl-sum denominator
#pragma unroll
        for (int r = 0; r < 4; r++) {
            int qrow = 4 * (l >> 4) + r;
            float pr[8], rs = 0.f;
#pragma unroll
            for (int kn = 0; kn < 8; kn++) {
                int kg = k0 + kn * 16 + (l & 15);
                float x = sa[kn][r] * 0.125f + REL[r * 8 + kn] - 16.0f;
                pr[kn] = (kg < len) ? __expf(x) : 0.0f;
                rs += pr[kn];
            }
#pragma unroll
            for (int o = 1; o < 16; o <<= 1) rs += __shfl_xor(rs, o, 64);
            l_run[r] += rs;
#pragma unroll
            for (int kn = 0; kn < 8; kn++) {
                int ck = (kn * 2 + ((l >> 3) & 1)) ^ (qrow & 15);
                Pw[qrow * 128 + ck * 8 + (l & 7)] = f2bf(pr[kn]);
            }
        }

        if (kt + 1 < nkt) {
            // need V(kt) landed; newer = K(kt+1)4 + REL(kt+1)32
            asm volatile("s_waitcnt vmcnt(36)" ::: "memory");
        } else {
            asm volatile("s_waitcnt vmcnt(0)" ::: "memory");
        }
        block_barrier();                     // barrier2: V visible to all waves

        // PV: out[q][d] += P[q,k]·V[k,d]
        __builtin_amdgcn_s_setprio(1);
#pragma unroll
        for (int s = 0; s < 4; s++) {
            int arow = (l & 15);
            bf16x8 pf = *(const bf16x8*)(Pw + arow * 128 + (((s * 4 + (l >> 4)) ^ arow) * 8));
#pragma unroll
            for (int dn = 0; dn < 4; dn++) {
                int drow = dn * 16 + (l & 15);
                bf16x8 vf = *(const bf16x8*)(Vs + drow * 128 + (((s * 4 + (l >> 4)) ^ (drow & 15)) * 8));
                oacc[dn] = __builtin_amdgcn_mfma_f32_16x16x32_bf16(pf, vf, oacc[dn], 0, 0, 0);
            }
        }
        __builtin_amdgcn_s_setprio(0);
        block_barrier();                     // barrier3: all PV reads of Vs done
        if (kt + 1 < nkt) STAGE_V(kt + 1);   // +4 overwrite Vs (covered by next vmcnt(36))
    };

    for (int kt = 0; kt < nkt; kt += 2) {
        tile_body(kt, rA, rB);
        if (kt + 1 < nkt) tile_body(kt + 1, rB, rA);
    }

    // epilogue: normalize, store bf16 to AO[b*1024+q][h*64+d]
    unsigned short* AOg = AO + ((size_t)(b * 1024 + q0 + w * 16)) * 512 + h * 64;
#pragma unroll
    for (int r = 0; r < 4; r++) {
        float inv = 1.0f / l_run[r];
        int qrow = 4 * (l >> 4) + r;
#pragma unroll
        for (int dn = 0; dn < 4; dn++)
            AOg[(size_t)qrow * 512 + dn * 16 + (l & 15)] = f2bf(oacc[dn][r] * inv);
    }
}

// ---------------- FF GEMM: out[m,n] = AO[m,:]·ff_w[n,:] + ff_b[n] (f32 out) ---
// 64x64 tiles, BK=32, 512 blocks = 2/CU, 1-deep prefetch (r16 green).
__global__ __launch_bounds__(256) void ff_kernel(
    const unsigned short* __restrict__ AO, const float* __restrict__ ff_w,
    const float* __restrict__ ff_b, float* __restrict__ out)
{
    const int t = threadIdx.x;
    const int l = t & 63;
    const int w = t >> 6;
    const int wm = w >> 1, wn = w & 1;       // 2x2 waves of 32x32
    const int wid = (blockIdx.x & 7) * 64 + (blockIdx.x >> 3);
    const int by = wid >> 3;                 // m tile (4096/64)
    const int bx = wid & 7;                  // n tile (512/64)
    const int m0 = by * 64, n0 = bx * 64;

    __shared__ __align__(16) unsigned short As[64 * 32];
    __shared__ __align__(16) unsigned short Bs[64 * 32];

    f32x4 acc[2][2];
#pragma unroll
    for (int i = 0; i < 2; i++)
#pragma unroll
        for (int j = 0; j < 2; j++) acc[i][j] = (f32x4){0.f, 0.f, 0.f, 0.f};

    uint4 ua;
    float4 rbf[2];
    const int arow = t >> 2, ac = t & 3;
    auto LOAD = [&](int k0) {
        ua = *(const uint4*)(AO + (size_t)(m0 + arow) * 512 + k0 + ac * 8);
#pragma unroll
        for (int i = 0; i < 2; i++) {
            int idx = t + 256 * i;
            int row = idx >> 3, c = idx & 7;
            rbf[i] = *(const float4*)(ff_w + (size_t)(n0 + row) * 512 + k0 + c * 4);
        }
    };
    LOAD(0);

    for (int k0 = 0; k0 < 512; k0 += 32) {
        if (k0) block_barrier();
        *(uint4*)(As + arow * 32 + ((ac ^ (arow & 3)) * 8)) = ua;
#pragma unroll
        for (int i = 0; i < 2; i++) {
            int idx = t + 256 * i;
            int row = idx >> 3, c = idx & 7;
            __align__(8) unsigned short vb[4] = {f2bf(rbf[i].x), f2bf(rbf[i].y), f2bf(rbf[i].z), f2bf(rbf[i].w)};
            *(uint2*)(Bs + row * 32 + (((c >> 1) ^ (row & 3)) * 8) + (c & 1) * 4) = *(uint2*)vb;
        }
        asm volatile("s_waitcnt lgkmcnt(0)" ::: "memory");
        block_barrier();
        if (k0 + 32 < 512) LOAD(k0 + 32);

        bf16x8 af[2], bfv[2];
#pragma unroll
        for (int mf = 0; mf < 2; mf++) {
            int row = wm * 32 + mf * 16 + (l & 15);
            af[mf] = *(const bf16x8*)(As + row * 32 + (((l >> 4) ^ (row & 3)) * 8));
        }
#pragma unroll
        for (int nf = 0; nf < 2; nf++) {
            int row = wn * 32 + nf * 16 + (l & 15);
            bfv[nf] = *(const bf16x8*)(Bs + row * 32 + (((l >> 4) ^ (row & 3)) * 8));
        }
#pragma unroll
        for (int mf = 0; mf < 2; mf++)
#pragma unroll
            for (int nf = 0; nf < 2; nf++)
                acc[mf][nf] = __builtin_amdgcn_mfma_f32_16x16x32_bf16(af[mf], bfv[nf], acc[mf][nf], 0, 0, 0);
    }

#pragma unroll
    for (int nf = 0; nf < 2; nf++) {
        int n = n0 + wn * 32 + nf * 16 + (l & 15);
        float bv = ff_b[n];
#pragma unroll
        for (int mf = 0; mf < 2; mf++) {
            int mbase = m0 + wm * 32 + mf * 16 + 4 * (l >> 4);
#pragma unroll
            for (int r = 0; r < 4; r++)
                out[(size_t)(mbase + r) * 512 + n] = acc[mf][nf][r] + bv;
        }
    }
}

extern "C" void kernel_launch(void* const* d_in, const int* in_sizes, int n_in,
                              void* d_out, int out_size, void* d_ws, size_t ws_size,
                              hipStream_t stream) {
    const float* key   = (const float*)d_in[0];
    const float* query = (const float*)d_in[1];
    const float* value = (const float*)d_in[2];
    const float* rel   = (const float*)d_in[3];
    const float* wk_w  = (const float*)d_in[4];
    const float* wk_b  = (const float*)d_in[5];
    const float* wq_w  = (const float*)d_in[6];
    const float* wq_b  = (const float*)d_in[7];
    const float* wv_w  = (const float*)d_in[8];
    const float* wv_b  = (const float*)d_in[9];
    const float* ff_w  = (const float*)d_in[10];
    const float* ff_b  = (const float*)d_in[11];
    const int* seq_len = (const int*)d_in[12];
    const int* lex_num = (const int*)d_in[13];
    float* out = (float*)d_out;

    unsigned short* Qb = (unsigned short*)d_ws;     // [4][8][1024][64] bf16, 4 MB
    unsigned short* Kb = Qb + 2097152;              // 4 MB
    unsigned short* Vt = Kb + 2097152;              // [4][8][64][1024] bf16, 4 MB
    unsigned short* AO = Vt + 2097152;              // [4096][512] bf16, 4 MB

    proj_kernel<<<dim3(768), 256, 0, stream>>>(query, key, value,
                                               wq_w, wq_b, wk_w, wk_b, wv_w, wv_b,
                                               Qb, Kb, Vt);
    attn_kernel<<<dim3(512), 256, 0, stream>>>(Qb, Kb, Vt, rel, seq_len, lex_num, AO);
    ff_kernel<<<dim3(512), 256, 0, stream>>>(AO, ff_w, ff_b, out);
}